// Round 1
// baseline (21403.040 us; speedup 1.0000x reference)
//
#include <hip/hip_runtime.h>

typedef __attribute__((ext_vector_type(8))) short short8;
typedef __attribute__((ext_vector_type(4))) float f32x4;

#define T_STEPS 512
#define BATCH 64
#define HID 1024
#define NWG 64
#define WROW 1032  // padded LDS row stride in shorts: 2064 B, 16B-aligned, 2-way banks (free)

__device__ __forceinline__ unsigned short f2bf(float f) {
  union { float f; unsigned u; } v; v.f = f;
  return (unsigned short)((v.u + 0x7FFFu + ((v.u >> 16) & 1u)) >> 16);
}

// ---------------- conversion ----------------
__global__ void k_f32_to_bf16(const float* __restrict__ src,
                              unsigned short* __restrict__ dst, int n4) {
  int i = blockIdx.x * blockDim.x + threadIdx.x;
  if (i >= n4) return;
  float4 v = ((const float4*)src)[i];
  unsigned long long p = (unsigned long long)f2bf(v.x)
                       | ((unsigned long long)f2bf(v.y) << 16)
                       | ((unsigned long long)f2bf(v.z) << 32)
                       | ((unsigned long long)f2bf(v.w) << 48);
  ((unsigned long long*)dst)[i] = p;
}

__global__ void k_sentinel(float* out) { out[threadIdx.x] = 12345.0f; }

// ---------------- big GEMM: C(M,N) = A(M,K) * B(N,K)^T + bias(N) ----------------
// M=32768 N=3072 K=1024, A/B bf16, C fp32. 128x128 tile, 4 waves of 64x64.
__global__ __launch_bounds__(256) void k_gemm_bias(
    const unsigned short* __restrict__ A,
    const unsigned short* __restrict__ Bm,
    const float* __restrict__ bias,
    float* __restrict__ C) {
  constexpr int K = 1024, N = 3072;
  constexpr int LS = 40;  // LDS row stride (shorts): 80 B, 16B-aligned, 2-way banks
  __shared__ unsigned short As[128 * LS];
  __shared__ unsigned short Bs[128 * LS];
  const int tid = threadIdx.x;
  const int lane = tid & 63;
  const int w = tid >> 6;
  const int wm = (w >> 1) * 64, wn = (w & 1) * 64;
  const int m0 = blockIdx.y * 128, n0 = blockIdx.x * 128;
  const int q = lane >> 4, ln = lane & 15;
  const int r = tid >> 2;
  const int c8 = (tid & 3) * 8;

  f32x4 acc[4][4] = {};

  for (int k0 = 0; k0 < K; k0 += 32) {
#pragma unroll
    for (int p = 0; p < 2; ++p) {
      int row = r + p * 64;
      *(short8*)&As[row * LS + c8] = *(const short8*)&A[(long)(m0 + row) * K + k0 + c8];
      *(short8*)&Bs[row * LS + c8] = *(const short8*)&Bm[(long)(n0 + row) * K + k0 + c8];
    }
    __syncthreads();
    short8 af[4], bfr[4];
#pragma unroll
    for (int i = 0; i < 4; ++i) af[i] = *(short8*)&As[(wm + i * 16 + ln) * LS + q * 8];
#pragma unroll
    for (int i = 0; i < 4; ++i) bfr[i] = *(short8*)&Bs[(wn + i * 16 + ln) * LS + q * 8];
#pragma unroll
    for (int im = 0; im < 4; ++im)
#pragma unroll
      for (int in = 0; in < 4; ++in)
        acc[im][in] = __builtin_amdgcn_mfma_f32_16x16x32_bf16(af[im], bfr[in], acc[im][in], 0, 0, 0);
    __syncthreads();
  }
#pragma unroll
  for (int im = 0; im < 4; ++im) {
    int mrow = m0 + wm + im * 16 + q * 4;
#pragma unroll
    for (int in = 0; in < 4; ++in) {
      int ncol = n0 + wn + in * 16 + ln;
      float bv = bias[ncol];
#pragma unroll
      for (int j = 0; j < 4; ++j)
        C[(long)(mrow + j) * N + ncol] = acc[im][in][j] + bv;
    }
  }
}

// ---------------- device-scope grid barrier (64 WGs) ----------------
// bar[0]=count, bar[1]=generation, bar[2]=dead flag
__device__ __forceinline__ void gbar(unsigned* bar, unsigned target) {
  __syncthreads();
  if (threadIdx.x == 0) {
    if (__hip_atomic_load(&bar[2], __ATOMIC_RELAXED, __HIP_MEMORY_SCOPE_AGENT) == 0u) {
      unsigned old = __hip_atomic_fetch_add(&bar[0], 1u, __ATOMIC_ACQ_REL, __HIP_MEMORY_SCOPE_AGENT);
      if (old == NWG - 1) {
        __hip_atomic_store(&bar[0], 0u, __ATOMIC_RELAXED, __HIP_MEMORY_SCOPE_AGENT);
        __hip_atomic_store(&bar[1], target, __ATOMIC_RELEASE, __HIP_MEMORY_SCOPE_AGENT);
      } else {
        long spins = 0;
        while (__hip_atomic_load(&bar[1], __ATOMIC_ACQUIRE, __HIP_MEMORY_SCOPE_AGENT) < target) {
          __builtin_amdgcn_s_sleep(2);
          if (++spins > (1L << 22)) {  // failsafe: wrong answer beats a hang
            __hip_atomic_store(&bar[2], 1u, __ATOMIC_RELAXED, __HIP_MEMORY_SCOPE_AGENT);
            break;
          }
        }
      }
    }
  }
  __syncthreads();
}

// ---------------- persistent GRU recurrence ----------------
// 64 WGs x 256 thr. WG owns 16 output features (c0..c0+15) for r,z,c; weights LDS-resident.
__global__ __launch_bounds__(256, 1) void k_gru_rec(
    const float* __restrict__ gx,           // (T,B,3,H) fp32
    const unsigned short* __restrict__ Wh,  // (3,H,H) bf16, this layer
    float* __restrict__ h32,                // (B,H) fp32 state
    unsigned short* __restrict__ h16,       // (B,H) bf16 state
    unsigned short* __restrict__ hr16,      // (B,H) bf16 h*r
    unsigned short* __restrict__ ys16,      // (T,B,H) bf16 (written when layer==0)
    float* __restrict__ outh,               // (T,B,H) fp32 d_out hidden (written when layer==1)
    float* __restrict__ outs,               // (B,H) fp32 d_out state slice for this layer
    unsigned* __restrict__ bar, int layer) {
  __shared__ unsigned short Ws[3 * 16 * WROW];  // 99,072 B
  const int tid = threadIdx.x;
  const int lane = tid & 63;
  const int wv = tid >> 6;
  const int q = lane >> 4, ln = lane & 15;
  const int c0 = blockIdx.x * 16;
  const int m0 = wv * 16;

  // stage weight slices: 3 gates x 16 rows x 1024 k  (6144 chunks of 8)
  for (int i = tid; i < 3 * 16 * 128; i += 256) {
    int g = i >> 11;
    int rem = i & 2047;
    int row = rem >> 7;
    int k8 = (rem & 127) * 8;
    *(short8*)&Ws[g * (16 * WROW) + row * WROW + k8] =
        *(const short8*)&Wh[((long)g * HID + (c0 + row)) * HID + k8];
  }
  __syncthreads();

  unsigned gen = 0;
  const int rowA = m0 + ln;      // A-fragment row for this lane
  const int jrow = m0 + q * 4;   // C/D base row

  for (int t = 0; t < T_STEPS; ++t) {
    const long tb = (long)t * BATCH;
    float gr[4], gz[4], gc[4], hold[4];
#pragma unroll
    for (int j = 0; j < 4; ++j) {
      long rowidx = (tb + jrow + j) * 3;
      gr[j] = gx[(rowidx + 0) * HID + c0 + ln];
      gz[j] = gx[(rowidx + 1) * HID + c0 + ln];
      gc[j] = gx[(rowidx + 2) * HID + c0 + ln];
      hold[j] = h32[(long)(jrow + j) * HID + c0 + ln];
    }
    // phase 1: r,z accumulate over full h
    f32x4 accr = {0.f, 0.f, 0.f, 0.f}, accz = {0.f, 0.f, 0.f, 0.f};
#pragma unroll 8
    for (int kk = 0; kk < 32; ++kk) {
      short8 a = *(const short8*)&h16[(long)rowA * HID + kk * 32 + q * 8];
      short8 br = *(const short8*)&Ws[0 * (16 * WROW) + ln * WROW + kk * 32 + q * 8];
      short8 bz = *(const short8*)&Ws[1 * (16 * WROW) + ln * WROW + kk * 32 + q * 8];
      accr = __builtin_amdgcn_mfma_f32_16x16x32_bf16(a, br, accr, 0, 0, 0);
      accz = __builtin_amdgcn_mfma_f32_16x16x32_bf16(a, bz, accz, 0, 0, 0);
    }
#pragma unroll
    for (int j = 0; j < 4; ++j) {
      float rr = 1.0f / (1.0f + __expf(-(gr[j] + accr[j])));
      hr16[(long)(jrow + j) * HID + c0 + ln] = f2bf(hold[j] * rr);
    }
    gbar(bar, ++gen);
    // phase 2: c accumulate over full h*r
    f32x4 accc = {0.f, 0.f, 0.f, 0.f};
#pragma unroll 8
    for (int kk = 0; kk < 32; ++kk) {
      short8 a = *(const short8*)&hr16[(long)rowA * HID + kk * 32 + q * 8];
      short8 bc = *(const short8*)&Ws[2 * (16 * WROW) + ln * WROW + kk * 32 + q * 8];
      accc = __builtin_amdgcn_mfma_f32_16x16x32_bf16(a, bc, accc, 0, 0, 0);
    }
#pragma unroll
    for (int j = 0; j < 4; ++j) {
      float zz = 1.0f / (1.0f + __expf(-(gz[j] + accz[j])));
      float cc = tanhf(gc[j] + accc[j]);
      float hn = zz * hold[j] + (1.0f - zz) * cc;
      long pos = (long)(jrow + j) * HID + c0 + ln;
      h32[pos] = hn;
      h16[pos] = f2bf(hn);
      if (layer == 0) ys16[(tb + jrow + j) * HID + c0 + ln] = f2bf(hn);
      else            outh[(tb + jrow + j) * HID + c0 + ln] = hn;
      if (t == T_STEPS - 1) outs[pos] = hn;
    }
    gbar(bar, ++gen);
  }
}

// ---------------- launch ----------------
extern "C" void kernel_launch(void* const* d_in, const int* in_sizes, int n_in,
                              void* d_out, int out_size, void* d_ws, size_t ws_size,
                              hipStream_t stream) {
  const float* x = (const float*)d_in[0];
  const float* Wx = (const float*)d_in[1];
  const float* bx = (const float*)d_in[2];
  const float* Wh = (const float*)d_in[3];
  float* out = (float*)d_out;

  const size_t SZ_GX = (size_t)T_STEPS * BATCH * 3 * HID * 4;   // 402,653,184
  const size_t SZ_HID = (size_t)T_STEPS * BATCH * HID * 2;      // 67,108,864
  const size_t SZ_W16 = (size_t)2 * 3 * HID * HID * 2;          // 12,582,912
  const size_t NEEDED = SZ_GX + SZ_HID + 2 * SZ_W16 +
                        (size_t)BATCH * HID * 4 + 2 * (size_t)BATCH * HID * 2 + 256;
  if (ws_size < NEEDED) {  // distinctive sentinel => diagnose ws_size, not math
    k_sentinel<<<1, 64, 0, stream>>>(out);
    return;
  }

  char* ws = (char*)d_ws;
  size_t off = 0;
  float* gx32 = (float*)(ws + off); off += SZ_GX;
  unsigned short* hid16 = (unsigned short*)(ws + off); off += SZ_HID;
  unsigned short* Wx16 = (unsigned short*)(ws + off); off += SZ_W16;
  unsigned short* Wh16 = (unsigned short*)(ws + off); off += SZ_W16;
  float* h32 = (float*)(ws + off); off += (size_t)BATCH * HID * 4;
  unsigned short* h16 = (unsigned short*)(ws + off); off += (size_t)BATCH * HID * 2;
  unsigned short* hr16 = (unsigned short*)(ws + off); off += (size_t)BATCH * HID * 2;
  unsigned* bar = (unsigned*)(ws + off); off += 256;

  {
    int n4 = T_STEPS * BATCH * HID / 4;
    k_f32_to_bf16<<<(n4 + 255) / 256, 256, 0, stream>>>(x, hid16, n4);
  }
  {
    int n4 = 2 * 3 * HID * HID / 4;
    k_f32_to_bf16<<<(n4 + 255) / 256, 256, 0, stream>>>(Wx, Wx16, n4);
    k_f32_to_bf16<<<(n4 + 255) / 256, 256, 0, stream>>>(Wh, Wh16, n4);
  }

  float* outh = out;
  float* outs = out + (size_t)T_STEPS * BATCH * HID;

  for (int l = 0; l < 2; ++l) {
    k_gemm_bias<<<dim3(3072 / 128, 32768 / 128), 256, 0, stream>>>(
        hid16, Wx16 + (size_t)l * 3 * HID * HID, bx + (size_t)l * 3 * HID, gx32);
    hipMemsetAsync(h32, 0, (size_t)BATCH * HID * 4, stream);
    hipMemsetAsync(h16, 0, (size_t)BATCH * HID * 2, stream);
    hipMemsetAsync(bar, 0, 256, stream);
    k_gru_rec<<<NWG, 256, 0, stream>>>(
        gx32, Wh16 + (size_t)l * 3 * HID * HID, h32, h16, hr16,
        hid16, outh, outs + (size_t)l * BATCH * HID, bar, l);
  }
}